// Round 3
// baseline (2040.496 us; speedup 1.0000x reference)
//
#include <hip/hip_runtime.h>
#include <hip/hip_bf16.h>

// RNNClassifier: B=64, T=2048, V=50000, E=256, H=256, O=16
// K0: W_ih/W_hh fp32 -> fp16 once into d_ws.
// K1 (MFMA f16): xh16[B*T][H] = fp16( emb[x] @ W_ih^T + b_ih + b_hh ).
// K2 (MFMA f16): scan. 16 WGs x 4 chains x 8 waves (512 thr, 2 waves/SIMD).
//   R1 structure, one fix: A-fragments (W_hh) are PINNED in VGPRs via an
//   asm-opacity barrier after the load. R1 compiled to VGPR_Count=64 --
//   the compiler rematerialized the afr global loads INSIDE the step loop
//   (legal: const __restrict__), so every timestep re-streamed 256B/lane of
//   weights from L2 with exposed vmcnt latency. That was the invariant
//   ~950 cyc/step overhead. "+v" makes the loaded value opaque -> must
//   stay register-resident (~165 VGPRs, fits 256-cap of (512,2)).
//   HP=272 keeps the 4-chain x 4-quad b128 reads 2-way banked (free).

#define B_  64
#define T_  2048
#define E_  256
#define H_  256
#define O_  16
#define H2_ 128
#define CH  4     // chains per WG
#define HP  272   // padded h stride (halves): 136 dwords ≡ 8 (mod 32)

typedef _Float16 f16x2 __attribute__((ext_vector_type(2)));
typedef _Float16 f16x4 __attribute__((ext_vector_type(4)));
typedef _Float16 f16x8 __attribute__((ext_vector_type(8)));
typedef float    f32x4 __attribute__((ext_vector_type(4)));

// Barrier without __syncthreads()'s vmcnt(0) drain. Safe: in-loop cross-wave
// communication is LDS-only.
#define LDS_BARRIER() asm volatile("s_waitcnt lgkmcnt(0)\n\ts_barrier" ::: "memory")

__device__ __forceinline__ float tanh_fast(float x) {
  const float e = __expf(2.0f * x);
  return fmaf(-2.0f, __builtin_amdgcn_rcpf(e + 1.0f), 1.0f);
}

__device__ __forceinline__ f32x4 cvt4(f16x4 v) {
  return (f32x4){(float)v[0], (float)v[1], (float)v[2], (float)v[3]};
}

// ---------------------------------------------------------------------------
__global__ __launch_bounds__(256) void k0_cvt(
    const float* __restrict__ W_ih, const float* __restrict__ W_hh,
    _Float16* __restrict__ Wih16, _Float16* __restrict__ Whh16) {
  const int i = (blockIdx.x * 256 + threadIdx.x) * 4;
  if (i < H_ * E_) {
    float4 a = *(const float4*)&W_ih[i];
    float4 b = *(const float4*)&W_hh[i];
    f16x4 ah, bh;
    ah[0]=(_Float16)a.x; ah[1]=(_Float16)a.y; ah[2]=(_Float16)a.z; ah[3]=(_Float16)a.w;
    bh[0]=(_Float16)b.x; bh[1]=(_Float16)b.y; bh[2]=(_Float16)b.z; bh[3]=(_Float16)b.w;
    *(f16x4*)&Wih16[i] = ah;
    *(f16x4*)&Whh16[i] = bh;
  }
}

// ---------------------------------------------------------------------------
// K1: gathered GEMM via MFMA (unchanged).
// ---------------------------------------------------------------------------
__global__ __launch_bounds__(256) void k1_xh(
    const int* __restrict__ x, const float* __restrict__ emb,
    const _Float16* __restrict__ Wih16, const float* __restrict__ b_ih,
    const float* __restrict__ b_hh, _Float16* __restrict__ xh) {
  __shared__ _Float16 A16[64][264];
  const int tid  = threadIdx.x;
  const int w    = tid >> 6;
  const int lane = tid & 63;
  const int nl   = lane & 15;
  const int koff = (lane >> 4) << 3;
  const long r0  = (long)blockIdx.x * 64;

  {
    const int c4 = lane << 2;
#pragma unroll
    for (int it = 0; it < 16; ++it) {
      const int row = (it << 2) + w;
      const long tok = x[r0 + row];
      const float4 v = *(const float4*)&emb[tok * E_ + c4];
      f16x4 hv;
      hv[0] = (_Float16)v.x; hv[1] = (_Float16)v.y;
      hv[2] = (_Float16)v.z; hv[3] = (_Float16)v.w;
      *(f16x4*)&A16[row][c4] = hv;
    }
  }

  f16x8 bfr[4][8];
#pragma unroll
  for (int nt = 0; nt < 4; ++nt) {
    const int n = (w << 6) + (nt << 4) + nl;
#pragma unroll
    for (int kt = 0; kt < 8; ++kt)
      bfr[nt][kt] = *(const f16x8*)&Wih16[n * E_ + (kt << 5) + koff];
  }
  __syncthreads();

  f32x4 acc[4][4];
#pragma unroll
  for (int mt = 0; mt < 4; ++mt)
#pragma unroll
    for (int nt = 0; nt < 4; ++nt) acc[mt][nt] = (f32x4){};

#pragma unroll
  for (int mt = 0; mt < 4; ++mt) {
#pragma unroll
    for (int kt = 0; kt < 8; ++kt) {
      const f16x8 a = *(const f16x8*)&A16[(mt << 4) + nl][(kt << 5) + koff];
#pragma unroll
      for (int nt = 0; nt < 4; ++nt)
        acc[mt][nt] = __builtin_amdgcn_mfma_f32_16x16x32_f16(a, bfr[nt][kt], acc[mt][nt], 0, 0, 0);
    }
  }
  __syncthreads();

  {
    const int rsub = (lane >> 4) << 2;
#pragma unroll
    for (int nt = 0; nt < 4; ++nt) {
      const int n = (w << 6) + (nt << 4) + nl;
      const float bias = b_ih[n] + b_hh[n];
#pragma unroll
      for (int mt = 0; mt < 4; ++mt)
#pragma unroll
        for (int j = 0; j < 4; ++j)
          A16[(mt << 4) + rsub + j][n] = (_Float16)(acc[mt][nt][j] + bias);
    }
  }
  __syncthreads();

  {
#pragma unroll
    for (int i = 0; i < 8; ++i) {
      const int row = (w << 4) + (i << 1) + (lane >> 5);
      const int col = (lane & 31) << 3;
      *(f16x8*)&xh[(r0 + row) * H_ + col] = *(const f16x8*)&A16[row][col];
    }
  }
}

// ---------------------------------------------------------------------------
// K2: 8-wave scan, 16 WGs x 512 thr. Wave w: rows [32w,32w+32), mt in {0,1}.
// Lane: nl=lane&15 -> B col; chain cc=nl&3; copy-group g=nl>>2 picks which
// (mt, row-pair) this lane tanh's and writes (4-way split of the 8 outputs).
// Per body: 8 ds_read b128 (4x broadcast) -> 16 MFMA (4 chains depth 4,
// C_in = cvt(xq) on the first half-chains) -> select 2 -> 2 tanh ->
// f16x2 write -> LDS_BARRIER. One barrier per step.
// ---------------------------------------------------------------------------
__global__ __launch_bounds__(512, 2) void k2_rnn(
    const _Float16* __restrict__ xh, const _Float16* __restrict__ Whh16,
    const float* __restrict__ fc1_w, const float* __restrict__ fc1_b,
    const float* __restrict__ fc2_w, const float* __restrict__ fc2_b,
    float* __restrict__ out) {
  __shared__ _Float16 h16[2][CH][HP];   // ping-pong hidden (fp16)
  __shared__ float    hid_s[CH][H2_ + 4];

  const int tid   = threadIdx.x;
  const int w     = tid >> 6;            // wave 0..7
  const int lane  = tid & 63;
  const int nl    = lane & 15;
  const int quad  = lane >> 4;
  const int cc    = nl & (CH - 1);       // chain (= B col mod 4)
  const int g     = nl >> 2;             // copy group 0..3
  const int mtsel = g & 1;               // which m-tile this lane finishes
  const int jp    = g >> 1;              // which row-pair this lane finishes
  const int koff  = quad << 3;
  const int rwb   = (w << 5) + (quad << 2);  // row base (mt adds 16)
  const int c0    = blockIdx.x * CH;

  // A-frags: W_hh rows 32w+16mt+nl (fp16), 64 VGPRs. PINNED: the "+v" asm
  // makes each fragment opaque so the compiler cannot rematerialize the
  // global load inside the step loop (R1 regression root cause).
  f16x8 afr[2][8];
#pragma unroll
  for (int mt = 0; mt < 2; ++mt) {
    const int r = (w << 5) + (mt << 4) + nl;
#pragma unroll
    for (int kt = 0; kt < 8; ++kt) {
      afr[mt][kt] = *(const f16x8*)&Whh16[r * H_ + (kt << 5) + koff];
      asm volatile("" : "+v"(afr[mt][kt]));
    }
  }

  // xh stream: chain cc, rows rwb(+16) of each step. Lanes nl>=4 duplicate
  // nl&3's addresses -> L1 dedup, no extra traffic.
  const _Float16* xb = xh + (size_t)(c0 + cc) * T_ * H_ + rwb;
  f16x4 xq0[4], xq1[4], xn0[4], xn1[4];   // mt=0 / mt=1, reg-resident relay
#pragma unroll
  for (int s = 0; s < 4; ++s) {
    xq0[s] = *(const f16x4*)&xb[(size_t)s * H_];
    xq1[s] = *(const f16x4*)&xb[(size_t)s * H_ + 16];
  }
#pragma unroll
  for (int s = 0; s < 4; ++s) {
    xn0[s] = *(const f16x4*)&xb[(size_t)(4 + s) * H_];
    xn1[s] = *(const f16x4*)&xb[(size_t)(4 + s) * H_ + 16];
  }

  // h0 = 0: zero used region [CH][0..256) of buffer 0 (1024 halves).
  if (tid < 128) *(f16x8*)&h16[0][tid >> 5][(tid & 31) << 3] = (f16x8){};
  __syncthreads();

#define BODY(P, S)                                                             \
  {                                                                            \
    f16x8 bfr[8];                                                              \
    _Pragma("unroll")                                                          \
    for (int i = 0; i < 8; ++i)                                                \
      bfr[i] = *(const f16x8*)&h16[P][cc][(i << 5) + koff];                    \
    f32x4 ca0 = __builtin_amdgcn_mfma_f32_16x16x32_f16(afr[0][0], bfr[0], cvt4(xq0[S]), 0, 0, 0); \
    f32x4 ca1 = __builtin_amdgcn_mfma_f32_16x16x32_f16(afr[1][0], bfr[0], cvt4(xq1[S]), 0, 0, 0); \
    f32x4 cb0 = __builtin_amdgcn_mfma_f32_16x16x32_f16(afr[0][4], bfr[4], (f32x4){}, 0, 0, 0); \
    f32x4 cb1 = __builtin_amdgcn_mfma_f32_16x16x32_f16(afr[1][4], bfr[4], (f32x4){}, 0, 0, 0); \
    _Pragma("unroll")                                                          \
    for (int i = 1; i < 4; ++i) {                                              \
      ca0 = __builtin_amdgcn_mfma_f32_16x16x32_f16(afr[0][i], bfr[i], ca0, 0, 0, 0);         \
      ca1 = __builtin_amdgcn_mfma_f32_16x16x32_f16(afr[1][i], bfr[i], ca1, 0, 0, 0);         \
      cb0 = __builtin_amdgcn_mfma_f32_16x16x32_f16(afr[0][4 + i], bfr[4 + i], cb0, 0, 0, 0); \
      cb1 = __builtin_amdgcn_mfma_f32_16x16x32_f16(afr[1][4 + i], bfr[4 + i], cb1, 0, 0, 0); \
    }                                                                          \
    const f32x4 s0 = ca0 + cb0;                                                \
    const f32x4 s1 = ca1 + cb1;                                                \
    const f32x4 sm = mtsel ? s1 : s0;                                          \
    const float u0 = jp ? sm[2] : sm[0];                                       \
    const float u1 = jp ? sm[3] : sm[1];                                       \
    f16x2 o;                                                                   \
    o[0] = (_Float16)tanh_fast(u0);                                            \
    o[1] = (_Float16)tanh_fast(u1);                                            \
    *(f16x2*)&h16[P ^ 1][cc][rwb + (mtsel << 4) + (jp << 1)] = o;              \
    LDS_BARRIER();                                                             \
  }

  for (int tt = 0; tt < T_; tt += 4) {
    BODY(0, 0)
    BODY(1, 1)
    BODY(0, 2)
    BODY(1, 3)
    // relay rotate: vmcnt wait lands here, on loads issued 4 bodies ago
#pragma unroll
    for (int s = 0; s < 4; ++s) { xq0[s] = xn0[s]; xq1[s] = xn1[s]; }
    const int tn = tt + 8;
#pragma unroll
    for (int s = 0; s < 4; ++s) {
      const size_t ti = (size_t)((tn + s) & (T_ - 1)) * H_;  // wrap; tail unused
      xn0[s] = *(const f16x4*)&xb[ti];
      xn1[s] = *(const f16x4*)&xb[ti + 16];
    }
  }
#undef BODY

  __syncthreads();  // final h(T) is in h16[0] (last body wrote buf 0)

  // MLP head. fc1: 4 chains x 128 outputs = 512 -> one per thread.
  {
    const int pc = tid >> 7;
    const int o_ = tid & 127;
    float s = fc1_b[o_];
#pragma unroll 8
    for (int k = 0; k < H_; ++k) s += fc1_w[o_ * H_ + k] * (float)h16[0][pc][k];
    hid_s[pc][o_] = fmaxf(s, 0.f);
  }
  __syncthreads();
  if (tid < CH * O_) {
    const int c = tid >> 4, o_ = tid & 15;
    float s = fc2_b[o_];
#pragma unroll 8
    for (int k = 0; k < H2_; ++k) s += fc2_w[o_ * H2_ + k] * hid_s[c][k];
    out[(size_t)(c0 + c) * O_ + o_] = s;
  }
}

extern "C" void kernel_launch(void* const* d_in, const int* in_sizes, int n_in,
                              void* d_out, int out_size, void* d_ws, size_t ws_size,
                              hipStream_t stream) {
  const int*   x     = (const int*)d_in[0];
  const float* emb   = (const float*)d_in[1];
  const float* W_ih  = (const float*)d_in[2];
  const float* W_hh  = (const float*)d_in[3];
  const float* b_ih  = (const float*)d_in[4];
  const float* b_hh  = (const float*)d_in[5];
  const float* fc1_w = (const float*)d_in[6];
  const float* fc1_b = (const float*)d_in[7];
  const float* fc2_w = (const float*)d_in[8];
  const float* fc2_b = (const float*)d_in[9];
  float* outp = (float*)d_out;

  _Float16* xh16  = (_Float16*)d_ws;                    // 64 MiB
  _Float16* Wih16 = xh16 + (size_t)B_ * T_ * H_;        // 128 KiB
  _Float16* Whh16 = Wih16 + (size_t)H_ * E_;            // 128 KiB

  k0_cvt<<<dim3(H_ * E_ / 1024), dim3(256), 0, stream>>>(W_ih, W_hh, Wih16, Whh16);
  k1_xh<<<dim3(B_ * T_ / 64), dim3(256), 0, stream>>>(x, emb, Wih16, b_ih, b_hh, xh16);
  k2_rnn<<<dim3(B_ / CH), dim3(512), 0, stream>>>(xh16, Whh16, fc1_w, fc1_b, fc2_w, fc2_b, outp);
}

// Round 4
// 1616.351 us; speedup vs baseline: 1.2624x; 1.2624x over previous
//
#include <hip/hip_runtime.h>
#include <hip/hip_bf16.h>

// RNNClassifier: B=64, T=2048, V=50000, E=256, H=256, O=16
// K0: W_ih/W_hh fp32 -> fp16 once into d_ws.
// K1 (MFMA f16): xh16[B*T][H] = fp16( emb[x] @ W_ih^T + b_ih + b_hh ).
// K2 (MFMA f16): scan. 16 WGs x 4 chains x 8 waves (512 thr, 2 waves/SIMD).
//   R1 structure + amdgpu_waves_per_eu(2,2). Root cause of the invariant
//   ~950cyc/step overhead: the backend MAXIMIZES occupancy (launch_bounds'
//   2nd arg is only a MIN), so it remat'ed (R1, VGPR=64, re-reading W_hh
//   from L2 every step) or spilled (R2 asm pin, scratch round-trips) the
//   64-VGPR afr file to hit 8 waves/SIMD -- occupancy that can never exist
//   (grid=16 WGs on 256 CUs -> 1 WG/CU). Clamping max waves/EU to 2 gives
//   RA a 256-VGPR budget; afr (~64) + bfr + relays fit with no remat/spill.
//   HP=272 keeps the 4-chain x 4-quad b128 reads 2-way banked (free).

#define B_  64
#define T_  2048
#define E_  256
#define H_  256
#define O_  16
#define H2_ 128
#define CH  4     // chains per WG
#define HP  272   // padded h stride (halves): 136 dwords ≡ 8 (mod 32)

typedef _Float16 f16x2 __attribute__((ext_vector_type(2)));
typedef _Float16 f16x4 __attribute__((ext_vector_type(4)));
typedef _Float16 f16x8 __attribute__((ext_vector_type(8)));
typedef float    f32x4 __attribute__((ext_vector_type(4)));

// Barrier without __syncthreads()'s vmcnt(0) drain. Safe: in-loop cross-wave
// communication is LDS-only.
#define LDS_BARRIER() asm volatile("s_waitcnt lgkmcnt(0)\n\ts_barrier" ::: "memory")

__device__ __forceinline__ float tanh_fast(float x) {
  const float e = __expf(2.0f * x);
  return fmaf(-2.0f, __builtin_amdgcn_rcpf(e + 1.0f), 1.0f);
}

__device__ __forceinline__ f32x4 cvt4(f16x4 v) {
  return (f32x4){(float)v[0], (float)v[1], (float)v[2], (float)v[3]};
}

// ---------------------------------------------------------------------------
__global__ __launch_bounds__(256) void k0_cvt(
    const float* __restrict__ W_ih, const float* __restrict__ W_hh,
    _Float16* __restrict__ Wih16, _Float16* __restrict__ Whh16) {
  const int i = (blockIdx.x * 256 + threadIdx.x) * 4;
  if (i < H_ * E_) {
    float4 a = *(const float4*)&W_ih[i];
    float4 b = *(const float4*)&W_hh[i];
    f16x4 ah, bh;
    ah[0]=(_Float16)a.x; ah[1]=(_Float16)a.y; ah[2]=(_Float16)a.z; ah[3]=(_Float16)a.w;
    bh[0]=(_Float16)b.x; bh[1]=(_Float16)b.y; bh[2]=(_Float16)b.z; bh[3]=(_Float16)b.w;
    *(f16x4*)&Wih16[i] = ah;
    *(f16x4*)&Whh16[i] = bh;
  }
}

// ---------------------------------------------------------------------------
// K1: gathered GEMM via MFMA (unchanged).
// ---------------------------------------------------------------------------
__global__ __launch_bounds__(256) void k1_xh(
    const int* __restrict__ x, const float* __restrict__ emb,
    const _Float16* __restrict__ Wih16, const float* __restrict__ b_ih,
    const float* __restrict__ b_hh, _Float16* __restrict__ xh) {
  __shared__ _Float16 A16[64][264];
  const int tid  = threadIdx.x;
  const int w    = tid >> 6;
  const int lane = tid & 63;
  const int nl   = lane & 15;
  const int koff = (lane >> 4) << 3;
  const long r0  = (long)blockIdx.x * 64;

  {
    const int c4 = lane << 2;
#pragma unroll
    for (int it = 0; it < 16; ++it) {
      const int row = (it << 2) + w;
      const long tok = x[r0 + row];
      const float4 v = *(const float4*)&emb[tok * E_ + c4];
      f16x4 hv;
      hv[0] = (_Float16)v.x; hv[1] = (_Float16)v.y;
      hv[2] = (_Float16)v.z; hv[3] = (_Float16)v.w;
      *(f16x4*)&A16[row][c4] = hv;
    }
  }

  f16x8 bfr[4][8];
#pragma unroll
  for (int nt = 0; nt < 4; ++nt) {
    const int n = (w << 6) + (nt << 4) + nl;
#pragma unroll
    for (int kt = 0; kt < 8; ++kt)
      bfr[nt][kt] = *(const f16x8*)&Wih16[n * E_ + (kt << 5) + koff];
  }
  __syncthreads();

  f32x4 acc[4][4];
#pragma unroll
  for (int mt = 0; mt < 4; ++mt)
#pragma unroll
    for (int nt = 0; nt < 4; ++nt) acc[mt][nt] = (f32x4){};

#pragma unroll
  for (int mt = 0; mt < 4; ++mt) {
#pragma unroll
    for (int kt = 0; kt < 8; ++kt) {
      const f16x8 a = *(const f16x8*)&A16[(mt << 4) + nl][(kt << 5) + koff];
#pragma unroll
      for (int nt = 0; nt < 4; ++nt)
        acc[mt][nt] = __builtin_amdgcn_mfma_f32_16x16x32_f16(a, bfr[nt][kt], acc[mt][nt], 0, 0, 0);
    }
  }
  __syncthreads();

  {
    const int rsub = (lane >> 4) << 2;
#pragma unroll
    for (int nt = 0; nt < 4; ++nt) {
      const int n = (w << 6) + (nt << 4) + nl;
      const float bias = b_ih[n] + b_hh[n];
#pragma unroll
      for (int mt = 0; mt < 4; ++mt)
#pragma unroll
        for (int j = 0; j < 4; ++j)
          A16[(mt << 4) + rsub + j][n] = (_Float16)(acc[mt][nt][j] + bias);
    }
  }
  __syncthreads();

  {
#pragma unroll
    for (int i = 0; i < 8; ++i) {
      const int row = (w << 4) + (i << 1) + (lane >> 5);
      const int col = (lane & 31) << 3;
      *(f16x8*)&xh[(r0 + row) * H_ + col] = *(const f16x8*)&A16[row][col];
    }
  }
}

// ---------------------------------------------------------------------------
// K2: 8-wave scan, 16 WGs x 512 thr. Wave w: rows [32w,32w+32), mt in {0,1}.
// Lane: nl=lane&15 -> B col; chain cc=nl&3; copy-group g=nl>>2 picks which
// (mt, row-pair) this lane tanh's and writes (4-way split of the 8 outputs).
// Per body: 8 ds_read b128 (4x broadcast) -> 16 MFMA (4 chains depth 4,
// C_in = cvt(xq) on the first half-chains) -> select 2 -> 2 tanh ->
// f16x2 write -> LDS_BARRIER. One barrier per step.
// ---------------------------------------------------------------------------
__global__ __attribute__((amdgpu_flat_work_group_size(512, 512)))
__attribute__((amdgpu_waves_per_eu(2, 2))) void k2_rnn(
    const _Float16* __restrict__ xh, const _Float16* __restrict__ Whh16,
    const float* __restrict__ fc1_w, const float* __restrict__ fc1_b,
    const float* __restrict__ fc2_w, const float* __restrict__ fc2_b,
    float* __restrict__ out) {
  __shared__ _Float16 h16[2][CH][HP];   // ping-pong hidden (fp16)
  __shared__ float    hid_s[CH][H2_ + 4];

  const int tid   = threadIdx.x;
  const int w     = tid >> 6;            // wave 0..7
  const int lane  = tid & 63;
  const int nl    = lane & 15;
  const int quad  = lane >> 4;
  const int cc    = nl & (CH - 1);       // chain (= B col mod 4)
  const int g     = nl >> 2;             // copy group 0..3
  const int mtsel = g & 1;               // which m-tile this lane finishes
  const int jp    = g >> 1;              // which row-pair this lane finishes
  const int koff  = quad << 3;
  const int rwb   = (w << 5) + (quad << 2);  // row base (mt adds 16)
  const int c0    = blockIdx.x * CH;

  // A-frags: W_hh rows 32w+16mt+nl (fp16), 64 VGPRs. With waves_per_eu
  // clamped to (2,2) the allocator has a 256-VGPR budget -> stays resident.
  f16x8 afr[2][8];
#pragma unroll
  for (int mt = 0; mt < 2; ++mt) {
    const int r = (w << 5) + (mt << 4) + nl;
#pragma unroll
    for (int kt = 0; kt < 8; ++kt)
      afr[mt][kt] = *(const f16x8*)&Whh16[r * H_ + (kt << 5) + koff];
  }

  // xh stream: chain cc, rows rwb(+16) of each step. Lanes nl>=4 duplicate
  // nl&3's addresses -> L1 dedup, no extra traffic.
  const _Float16* xb = xh + (size_t)(c0 + cc) * T_ * H_ + rwb;
  f16x4 xq0[4], xq1[4], xn0[4], xn1[4];   // mt=0 / mt=1, reg-resident relay
#pragma unroll
  for (int s = 0; s < 4; ++s) {
    xq0[s] = *(const f16x4*)&xb[(size_t)s * H_];
    xq1[s] = *(const f16x4*)&xb[(size_t)s * H_ + 16];
  }
#pragma unroll
  for (int s = 0; s < 4; ++s) {
    xn0[s] = *(const f16x4*)&xb[(size_t)(4 + s) * H_];
    xn1[s] = *(const f16x4*)&xb[(size_t)(4 + s) * H_ + 16];
  }

  // h0 = 0: zero used region [CH][0..256) of buffer 0 (1024 halves).
  if (tid < 128) *(f16x8*)&h16[0][tid >> 5][(tid & 31) << 3] = (f16x8){};
  __syncthreads();

#define BODY(P, S)                                                             \
  {                                                                            \
    f16x8 bfr[8];                                                              \
    _Pragma("unroll")                                                          \
    for (int i = 0; i < 8; ++i)                                                \
      bfr[i] = *(const f16x8*)&h16[P][cc][(i << 5) + koff];                    \
    f32x4 ca0 = __builtin_amdgcn_mfma_f32_16x16x32_f16(afr[0][0], bfr[0], cvt4(xq0[S]), 0, 0, 0); \
    f32x4 ca1 = __builtin_amdgcn_mfma_f32_16x16x32_f16(afr[1][0], bfr[0], cvt4(xq1[S]), 0, 0, 0); \
    f32x4 cb0 = __builtin_amdgcn_mfma_f32_16x16x32_f16(afr[0][4], bfr[4], (f32x4){}, 0, 0, 0); \
    f32x4 cb1 = __builtin_amdgcn_mfma_f32_16x16x32_f16(afr[1][4], bfr[4], (f32x4){}, 0, 0, 0); \
    _Pragma("unroll")                                                          \
    for (int i = 1; i < 4; ++i) {                                              \
      ca0 = __builtin_amdgcn_mfma_f32_16x16x32_f16(afr[0][i], bfr[i], ca0, 0, 0, 0);         \
      ca1 = __builtin_amdgcn_mfma_f32_16x16x32_f16(afr[1][i], bfr[i], ca1, 0, 0, 0);         \
      cb0 = __builtin_amdgcn_mfma_f32_16x16x32_f16(afr[0][4 + i], bfr[4 + i], cb0, 0, 0, 0); \
      cb1 = __builtin_amdgcn_mfma_f32_16x16x32_f16(afr[1][4 + i], bfr[4 + i], cb1, 0, 0, 0); \
    }                                                                          \
    const f32x4 s0 = ca0 + cb0;                                                \
    const f32x4 s1 = ca1 + cb1;                                                \
    const f32x4 sm = mtsel ? s1 : s0;                                          \
    const float u0 = jp ? sm[2] : sm[0];                                       \
    const float u1 = jp ? sm[3] : sm[1];                                       \
    f16x2 o;                                                                   \
    o[0] = (_Float16)tanh_fast(u0);                                            \
    o[1] = (_Float16)tanh_fast(u1);                                            \
    *(f16x2*)&h16[P ^ 1][cc][rwb + (mtsel << 4) + (jp << 1)] = o;              \
    LDS_BARRIER();                                                             \
  }

  for (int tt = 0; tt < T_; tt += 4) {
    BODY(0, 0)
    BODY(1, 1)
    BODY(0, 2)
    BODY(1, 3)
    // relay rotate: vmcnt wait lands here, on loads issued 4 bodies ago
#pragma unroll
    for (int s = 0; s < 4; ++s) { xq0[s] = xn0[s]; xq1[s] = xn1[s]; }
    const int tn = tt + 8;
#pragma unroll
    for (int s = 0; s < 4; ++s) {
      const size_t ti = (size_t)((tn + s) & (T_ - 1)) * H_;  // wrap; tail unused
      xn0[s] = *(const f16x4*)&xb[ti];
      xn1[s] = *(const f16x4*)&xb[ti + 16];
    }
  }
#undef BODY

  __syncthreads();  // final h(T) is in h16[0] (last body wrote buf 0)

  // MLP head. fc1: 4 chains x 128 outputs = 512 -> one per thread.
  {
    const int pc = tid >> 7;
    const int o_ = tid & 127;
    float s = fc1_b[o_];
#pragma unroll 8
    for (int k = 0; k < H_; ++k) s += fc1_w[o_ * H_ + k] * (float)h16[0][pc][k];
    hid_s[pc][o_] = fmaxf(s, 0.f);
  }
  __syncthreads();
  if (tid < CH * O_) {
    const int c = tid >> 4, o_ = tid & 15;
    float s = fc2_b[o_];
#pragma unroll 8
    for (int k = 0; k < H2_; ++k) s += fc2_w[o_ * H2_ + k] * hid_s[c][k];
    out[(size_t)(c0 + c) * O_ + o_] = s;
  }
}

extern "C" void kernel_launch(void* const* d_in, const int* in_sizes, int n_in,
                              void* d_out, int out_size, void* d_ws, size_t ws_size,
                              hipStream_t stream) {
  const int*   x     = (const int*)d_in[0];
  const float* emb   = (const float*)d_in[1];
  const float* W_ih  = (const float*)d_in[2];
  const float* W_hh  = (const float*)d_in[3];
  const float* b_ih  = (const float*)d_in[4];
  const float* b_hh  = (const float*)d_in[5];
  const float* fc1_w = (const float*)d_in[6];
  const float* fc1_b = (const float*)d_in[7];
  const float* fc2_w = (const float*)d_in[8];
  const float* fc2_b = (const float*)d_in[9];
  float* outp = (float*)d_out;

  _Float16* xh16  = (_Float16*)d_ws;                    // 64 MiB
  _Float16* Wih16 = xh16 + (size_t)B_ * T_ * H_;        // 128 KiB
  _Float16* Whh16 = Wih16 + (size_t)H_ * E_;            // 128 KiB

  k0_cvt<<<dim3(H_ * E_ / 1024), dim3(256), 0, stream>>>(W_ih, W_hh, Wih16, Whh16);
  k1_xh<<<dim3(B_ * T_ / 64), dim3(256), 0, stream>>>(x, emb, Wih16, b_ih, b_hh, xh16);
  k2_rnn<<<dim3(B_ / CH), dim3(512), 0, stream>>>(xh16, Whh16, fc1_w, fc1_b, fc2_w, fc2_b, outp);
}

// Round 5
// 1312.383 us; speedup vs baseline: 1.5548x; 1.2316x over previous
//
#include <hip/hip_runtime.h>
#include <hip/hip_bf16.h>

// RNNClassifier: B=64, T=2048, V=50000, E=256, H=256, O=16
// K0: W_ih/W_hh fp32 -> fp16 once into d_ws.
// K1 (MFMA f16): xh16[B*T][H] = fp16( emb[x] @ W_ih^T + b_ih + b_hh ).
// K2 (MFMA f16): scan. 16 WGs x 4 chains x 8 waves (512 thr, 2 waves/SIMD).
//   R1 loop structure; weights sourced from LDS. R1/R2/R3 all failed to keep
//   the 64-VGPR afr (W_hh fragments) register-resident: global loads from a
//   const __restrict__ pointer are provably invariant, so LLVM remats them
//   inside the step loop (VGPR=64/88 measured) regardless of occupancy
//   attributes, re-streaming 256B/lane/step from L2 with exposed latency.
//   Fix: stage W_hh into LDS once (128 KiB; total LDS 137.5 KiB < 160),
//   load afr from LDS pre-loop. ds_read cannot be remat'ed/sunk past the
//   "memory"-clobber barriers -> values MUST stay live in VGPRs.
//   Validation: VGPR_Count ~160-200, WRITE_SIZE stays ~4KB (no spill).
//   HP=272 keeps the 4-chain x 4-quad b128 reads 2-way banked (free).

#define B_  64
#define T_  2048
#define E_  256
#define H_  256
#define O_  16
#define H2_ 128
#define CH  4     // chains per WG
#define HP  272   // padded h stride (halves): 136 dwords ≡ 8 (mod 32)

typedef _Float16 f16x2 __attribute__((ext_vector_type(2)));
typedef _Float16 f16x4 __attribute__((ext_vector_type(4)));
typedef _Float16 f16x8 __attribute__((ext_vector_type(8)));
typedef float    f32x4 __attribute__((ext_vector_type(4)));

// Barrier without __syncthreads()'s vmcnt(0) drain. Safe: in-loop cross-wave
// communication is LDS-only.
#define LDS_BARRIER() asm volatile("s_waitcnt lgkmcnt(0)\n\ts_barrier" ::: "memory")

__device__ __forceinline__ float tanh_fast(float x) {
  const float e = __expf(2.0f * x);
  return fmaf(-2.0f, __builtin_amdgcn_rcpf(e + 1.0f), 1.0f);
}

__device__ __forceinline__ f32x4 cvt4(f16x4 v) {
  return (f32x4){(float)v[0], (float)v[1], (float)v[2], (float)v[3]};
}

// ---------------------------------------------------------------------------
__global__ __launch_bounds__(256) void k0_cvt(
    const float* __restrict__ W_ih, const float* __restrict__ W_hh,
    _Float16* __restrict__ Wih16, _Float16* __restrict__ Whh16) {
  const int i = (blockIdx.x * 256 + threadIdx.x) * 4;
  if (i < H_ * E_) {
    float4 a = *(const float4*)&W_ih[i];
    float4 b = *(const float4*)&W_hh[i];
    f16x4 ah, bh;
    ah[0]=(_Float16)a.x; ah[1]=(_Float16)a.y; ah[2]=(_Float16)a.z; ah[3]=(_Float16)a.w;
    bh[0]=(_Float16)b.x; bh[1]=(_Float16)b.y; bh[2]=(_Float16)b.z; bh[3]=(_Float16)b.w;
    *(f16x4*)&Wih16[i] = ah;
    *(f16x4*)&Whh16[i] = bh;
  }
}

// ---------------------------------------------------------------------------
// K1: gathered GEMM via MFMA (unchanged).
// ---------------------------------------------------------------------------
__global__ __launch_bounds__(256) void k1_xh(
    const int* __restrict__ x, const float* __restrict__ emb,
    const _Float16* __restrict__ Wih16, const float* __restrict__ b_ih,
    const float* __restrict__ b_hh, _Float16* __restrict__ xh) {
  __shared__ _Float16 A16[64][264];
  const int tid  = threadIdx.x;
  const int w    = tid >> 6;
  const int lane = tid & 63;
  const int nl   = lane & 15;
  const int koff = (lane >> 4) << 3;
  const long r0  = (long)blockIdx.x * 64;

  {
    const int c4 = lane << 2;
#pragma unroll
    for (int it = 0; it < 16; ++it) {
      const int row = (it << 2) + w;
      const long tok = x[r0 + row];
      const float4 v = *(const float4*)&emb[tok * E_ + c4];
      f16x4 hv;
      hv[0] = (_Float16)v.x; hv[1] = (_Float16)v.y;
      hv[2] = (_Float16)v.z; hv[3] = (_Float16)v.w;
      *(f16x4*)&A16[row][c4] = hv;
    }
  }

  f16x8 bfr[4][8];
#pragma unroll
  for (int nt = 0; nt < 4; ++nt) {
    const int n = (w << 6) + (nt << 4) + nl;
#pragma unroll
    for (int kt = 0; kt < 8; ++kt)
      bfr[nt][kt] = *(const f16x8*)&Wih16[n * E_ + (kt << 5) + koff];
  }
  __syncthreads();

  f32x4 acc[4][4];
#pragma unroll
  for (int mt = 0; mt < 4; ++mt)
#pragma unroll
    for (int nt = 0; nt < 4; ++nt) acc[mt][nt] = (f32x4){};

#pragma unroll
  for (int mt = 0; mt < 4; ++mt) {
#pragma unroll
    for (int kt = 0; kt < 8; ++kt) {
      const f16x8 a = *(const f16x8*)&A16[(mt << 4) + nl][(kt << 5) + koff];
#pragma unroll
      for (int nt = 0; nt < 4; ++nt)
        acc[mt][nt] = __builtin_amdgcn_mfma_f32_16x16x32_f16(a, bfr[nt][kt], acc[mt][nt], 0, 0, 0);
    }
  }
  __syncthreads();

  {
    const int rsub = (lane >> 4) << 2;
#pragma unroll
    for (int nt = 0; nt < 4; ++nt) {
      const int n = (w << 6) + (nt << 4) + nl;
      const float bias = b_ih[n] + b_hh[n];
#pragma unroll
      for (int mt = 0; mt < 4; ++mt)
#pragma unroll
        for (int j = 0; j < 4; ++j)
          A16[(mt << 4) + rsub + j][n] = (_Float16)(acc[mt][nt][j] + bias);
    }
  }
  __syncthreads();

  {
#pragma unroll
    for (int i = 0; i < 8; ++i) {
      const int row = (w << 4) + (i << 1) + (lane >> 5);
      const int col = (lane & 31) << 3;
      *(f16x8*)&xh[(r0 + row) * H_ + col] = *(const f16x8*)&A16[row][col];
    }
  }
}

// ---------------------------------------------------------------------------
// K2: 8-wave scan, 16 WGs x 512 thr. Wave w: rows [32w,32w+32), mt in {0,1}.
// Lane: nl=lane&15 -> B col; chain cc=nl&3; copy-group g=nl>>2 picks which
// (mt, row-pair) this lane tanh's and writes (4-way split of the 8 outputs).
// Per body: 8 ds_read b128 (4x broadcast) -> 16 MFMA (4 chains depth 4,
// C_in = cvt(xq) on the first half-chains) -> select 2 -> 2 tanh ->
// f16x2 write -> LDS_BARRIER. One barrier per step.
// ---------------------------------------------------------------------------
__global__ __attribute__((amdgpu_flat_work_group_size(512, 512)))
__attribute__((amdgpu_waves_per_eu(2, 2))) void k2_rnn(
    const _Float16* __restrict__ xh, const _Float16* __restrict__ Whh16,
    const float* __restrict__ fc1_w, const float* __restrict__ fc1_b,
    const float* __restrict__ fc2_w, const float* __restrict__ fc2_b,
    float* __restrict__ out) {
  __shared__ _Float16 whh_s[H_ * H_];   // 128 KiB staged W_hh (row-major)
  __shared__ _Float16 h16[2][CH][HP];   // ping-pong hidden (fp16)
  __shared__ float    hid_s[CH][H2_ + 4];

  const int tid   = threadIdx.x;
  const int w     = tid >> 6;            // wave 0..7
  const int lane  = tid & 63;
  const int nl    = lane & 15;
  const int quad  = lane >> 4;
  const int cc    = nl & (CH - 1);       // chain (= B col mod 4)
  const int g     = nl >> 2;             // copy group 0..3
  const int mtsel = g & 1;               // which m-tile this lane finishes
  const int jp    = g >> 1;              // which row-pair this lane finishes
  const int koff  = quad << 3;
  const int rwb   = (w << 5) + (quad << 2);  // row base (mt adds 16)
  const int c0    = blockIdx.x * CH;

  // Stage W_hh into LDS: linear coalesced copy, 512 thr x 16 rounds x 16 B.
  {
#pragma unroll
    for (int c = 0; c < 16; ++c) {
      const int idx = ((c << 9) + tid) << 3;
      *(f16x8*)&whh_s[idx] = *(const f16x8*)&Whh16[idx];
    }
  }
  // h0 = 0: zero used region [CH][0..256) of buffer 0 (1024 halves).
  if (tid < 128) *(f16x8*)&h16[0][tid >> 5][(tid & 31) << 3] = (f16x8){};
  __syncthreads();

  // A-frags from LDS: W_hh rows 32w+16mt+nl, 64 VGPRs. ds_read results
  // cannot be remat'ed past the in-loop "memory"-clobber barriers -> the
  // values are forced register-resident (the R1/R3 remat is illegal here).
  f16x8 afr[2][8];
#pragma unroll
  for (int mt = 0; mt < 2; ++mt) {
    const int r = (w << 5) + (mt << 4) + nl;
#pragma unroll
    for (int kt = 0; kt < 8; ++kt)
      afr[mt][kt] = *(const f16x8*)&whh_s[r * H_ + (kt << 5) + koff];
  }

  // xh stream: chain cc, rows rwb(+16) of each step. Lanes nl>=4 duplicate
  // nl&3's addresses -> L1 dedup, no extra traffic.
  const _Float16* xb = xh + (size_t)(c0 + cc) * T_ * H_ + rwb;
  f16x4 xq0[4], xq1[4], xn0[4], xn1[4];   // mt=0 / mt=1, reg-resident relay
#pragma unroll
  for (int s = 0; s < 4; ++s) {
    xq0[s] = *(const f16x4*)&xb[(size_t)s * H_];
    xq1[s] = *(const f16x4*)&xb[(size_t)s * H_ + 16];
  }
#pragma unroll
  for (int s = 0; s < 4; ++s) {
    xn0[s] = *(const f16x4*)&xb[(size_t)(4 + s) * H_];
    xn1[s] = *(const f16x4*)&xb[(size_t)(4 + s) * H_ + 16];
  }

#define BODY(P, S)                                                             \
  {                                                                            \
    f16x8 bfr[8];                                                              \
    _Pragma("unroll")                                                          \
    for (int i = 0; i < 8; ++i)                                                \
      bfr[i] = *(const f16x8*)&h16[P][cc][(i << 5) + koff];                    \
    f32x4 ca0 = __builtin_amdgcn_mfma_f32_16x16x32_f16(afr[0][0], bfr[0], cvt4(xq0[S]), 0, 0, 0); \
    f32x4 ca1 = __builtin_amdgcn_mfma_f32_16x16x32_f16(afr[1][0], bfr[0], cvt4(xq1[S]), 0, 0, 0); \
    f32x4 cb0 = __builtin_amdgcn_mfma_f32_16x16x32_f16(afr[0][4], bfr[4], (f32x4){}, 0, 0, 0); \
    f32x4 cb1 = __builtin_amdgcn_mfma_f32_16x16x32_f16(afr[1][4], bfr[4], (f32x4){}, 0, 0, 0); \
    _Pragma("unroll")                                                          \
    for (int i = 1; i < 4; ++i) {                                              \
      ca0 = __builtin_amdgcn_mfma_f32_16x16x32_f16(afr[0][i], bfr[i], ca0, 0, 0, 0);         \
      ca1 = __builtin_amdgcn_mfma_f32_16x16x32_f16(afr[1][i], bfr[i], ca1, 0, 0, 0);         \
      cb0 = __builtin_amdgcn_mfma_f32_16x16x32_f16(afr[0][4 + i], bfr[4 + i], cb0, 0, 0, 0); \
      cb1 = __builtin_amdgcn_mfma_f32_16x16x32_f16(afr[1][4 + i], bfr[4 + i], cb1, 0, 0, 0); \
    }                                                                          \
    const f32x4 s0 = ca0 + cb0;                                                \
    const f32x4 s1 = ca1 + cb1;                                                \
    const f32x4 sm = mtsel ? s1 : s0;                                          \
    const float u0 = jp ? sm[2] : sm[0];                                       \
    const float u1 = jp ? sm[3] : sm[1];                                       \
    f16x2 o;                                                                   \
    o[0] = (_Float16)tanh_fast(u0);                                            \
    o[1] = (_Float16)tanh_fast(u1);                                            \
    *(f16x2*)&h16[P ^ 1][cc][rwb + (mtsel << 4) + (jp << 1)] = o;              \
    LDS_BARRIER();                                                             \
  }

  for (int tt = 0; tt < T_; tt += 4) {
    BODY(0, 0)
    BODY(1, 1)
    BODY(0, 2)
    BODY(1, 3)
    // relay rotate: vmcnt wait lands here, on loads issued 4 bodies ago
#pragma unroll
    for (int s = 0; s < 4; ++s) { xq0[s] = xn0[s]; xq1[s] = xn1[s]; }
    const int tn = tt + 8;
#pragma unroll
    for (int s = 0; s < 4; ++s) {
      const size_t ti = (size_t)((tn + s) & (T_ - 1)) * H_;  // wrap; tail unused
      xn0[s] = *(const f16x4*)&xb[ti];
      xn1[s] = *(const f16x4*)&xb[ti + 16];
    }
  }
#undef BODY

  __syncthreads();  // final h(T) is in h16[0] (last body wrote buf 0)

  // MLP head. fc1: 4 chains x 128 outputs = 512 -> one per thread.
  {
    const int pc = tid >> 7;
    const int o_ = tid & 127;
    float s = fc1_b[o_];
#pragma unroll 8
    for (int k = 0; k < H_; ++k) s += fc1_w[o_ * H_ + k] * (float)h16[0][pc][k];
    hid_s[pc][o_] = fmaxf(s, 0.f);
  }
  __syncthreads();
  if (tid < CH * O_) {
    const int c = tid >> 4, o_ = tid & 15;
    float s = fc2_b[o_];
#pragma unroll 8
    for (int k = 0; k < H2_; ++k) s += fc2_w[o_ * H2_ + k] * hid_s[c][k];
    out[(size_t)(c0 + c) * O_ + o_] = s;
  }
}

extern "C" void kernel_launch(void* const* d_in, const int* in_sizes, int n_in,
                              void* d_out, int out_size, void* d_ws, size_t ws_size,
                              hipStream_t stream) {
  const int*   x     = (const int*)d_in[0];
  const float* emb   = (const float*)d_in[1];
  const float* W_ih  = (const float*)d_in[2];
  const float* W_hh  = (const float*)d_in[3];
  const float* b_ih  = (const float*)d_in[4];
  const float* b_hh  = (const float*)d_in[5];
  const float* fc1_w = (const float*)d_in[6];
  const float* fc1_b = (const float*)d_in[7];
  const float* fc2_w = (const float*)d_in[8];
  const float* fc2_b = (const float*)d_in[9];
  float* outp = (float*)d_out;

  _Float16* xh16  = (_Float16*)d_ws;                    // 64 MiB
  _Float16* Wih16 = xh16 + (size_t)B_ * T_ * H_;        // 128 KiB
  _Float16* Whh16 = Wih16 + (size_t)H_ * E_;            // 128 KiB

  k0_cvt<<<dim3(H_ * E_ / 1024), dim3(256), 0, stream>>>(W_ih, W_hh, Wih16, Whh16);
  k1_xh<<<dim3(B_ * T_ / 64), dim3(256), 0, stream>>>(x, emb, Wih16, b_ih, b_hh, xh16);
  k2_rnn<<<dim3(B_ / CH), dim3(512), 0, stream>>>(xh16, Whh16, fc1_w, fc1_b, fc2_w, fc2_b, outp);
}

// Round 6
// 1294.434 us; speedup vs baseline: 1.5764x; 1.0139x over previous
//
#include <hip/hip_runtime.h>
#include <hip/hip_bf16.h>

// RNNClassifier: B=64, T=2048, V=50000, E=256, H=256, O=16
// K0: W_ih/W_hh fp32 -> fp16 once into d_ws.
// K1 (MFMA f16): xh16[B*T][H] = fp16( emb[x] @ W_ih^T + b_ih + b_hh ).
// K2 (MFMA f16): scan. 16 WGs x 4 chains x 16 waves (1024 thr, 4 waves/SIMD).
//   R4 (LDS-staged W_hh, verified resident via AGPRs: in-loop bank-conflict
//   delta only 28cyc/step) left step=1372cyc vs the invariant 512cyc matrix
//   floor (32 MFMA/SIMD x 16cyc): the serial body chain {barrier->ds_read->
//   4-deep MFMA->adds->tanh->write->barrier} isn't hidden by 2 lockstep
//   waves/SIMD. This round: same CH=4 layout, but each wave owns ONE 16-row
//   m-tile (8 MFMA, two 4-deep chains) and 16 waves cover the 256 rows ->
//   4 waves/SIMD of independent pipelines overlap the shared matrix issue.
//   Tail shrinks to 1 tanh + 1 scalar write/lane (copy-group g picks one of
//   the 4 C-rows; static extracts + cndmask only). ~100 live VGPR < 128
//   budget at waves_per_eu(4,4).
//   HP=272 keeps the 4-chain x 4-quad b128 reads 2-way banked (free).

#define B_  64
#define T_  2048
#define E_  256
#define H_  256
#define O_  16
#define H2_ 128
#define CH  4     // chains per WG
#define HP  272   // padded h stride (halves): 136 dwords ≡ 8 (mod 32)

typedef _Float16 f16x2 __attribute__((ext_vector_type(2)));
typedef _Float16 f16x4 __attribute__((ext_vector_type(4)));
typedef _Float16 f16x8 __attribute__((ext_vector_type(8)));
typedef float    f32x4 __attribute__((ext_vector_type(4)));

// Barrier without __syncthreads()'s vmcnt(0) drain. Safe: in-loop cross-wave
// communication is LDS-only.
#define LDS_BARRIER() asm volatile("s_waitcnt lgkmcnt(0)\n\ts_barrier" ::: "memory")

__device__ __forceinline__ float tanh_fast(float x) {
  const float e = __expf(2.0f * x);
  return fmaf(-2.0f, __builtin_amdgcn_rcpf(e + 1.0f), 1.0f);
}

__device__ __forceinline__ f32x4 cvt4(f16x4 v) {
  return (f32x4){(float)v[0], (float)v[1], (float)v[2], (float)v[3]};
}

// ---------------------------------------------------------------------------
__global__ __launch_bounds__(256) void k0_cvt(
    const float* __restrict__ W_ih, const float* __restrict__ W_hh,
    _Float16* __restrict__ Wih16, _Float16* __restrict__ Whh16) {
  const int i = (blockIdx.x * 256 + threadIdx.x) * 4;
  if (i < H_ * E_) {
    float4 a = *(const float4*)&W_ih[i];
    float4 b = *(const float4*)&W_hh[i];
    f16x4 ah, bh;
    ah[0]=(_Float16)a.x; ah[1]=(_Float16)a.y; ah[2]=(_Float16)a.z; ah[3]=(_Float16)a.w;
    bh[0]=(_Float16)b.x; bh[1]=(_Float16)b.y; bh[2]=(_Float16)b.z; bh[3]=(_Float16)b.w;
    *(f16x4*)&Wih16[i] = ah;
    *(f16x4*)&Whh16[i] = bh;
  }
}

// ---------------------------------------------------------------------------
// K1: gathered GEMM via MFMA (unchanged).
// ---------------------------------------------------------------------------
__global__ __launch_bounds__(256) void k1_xh(
    const int* __restrict__ x, const float* __restrict__ emb,
    const _Float16* __restrict__ Wih16, const float* __restrict__ b_ih,
    const float* __restrict__ b_hh, _Float16* __restrict__ xh) {
  __shared__ _Float16 A16[64][264];
  const int tid  = threadIdx.x;
  const int w    = tid >> 6;
  const int lane = tid & 63;
  const int nl   = lane & 15;
  const int koff = (lane >> 4) << 3;
  const long r0  = (long)blockIdx.x * 64;

  {
    const int c4 = lane << 2;
#pragma unroll
    for (int it = 0; it < 16; ++it) {
      const int row = (it << 2) + w;
      const long tok = x[r0 + row];
      const float4 v = *(const float4*)&emb[tok * E_ + c4];
      f16x4 hv;
      hv[0] = (_Float16)v.x; hv[1] = (_Float16)v.y;
      hv[2] = (_Float16)v.z; hv[3] = (_Float16)v.w;
      *(f16x4*)&A16[row][c4] = hv;
    }
  }

  f16x8 bfr[4][8];
#pragma unroll
  for (int nt = 0; nt < 4; ++nt) {
    const int n = (w << 6) + (nt << 4) + nl;
#pragma unroll
    for (int kt = 0; kt < 8; ++kt)
      bfr[nt][kt] = *(const f16x8*)&Wih16[n * E_ + (kt << 5) + koff];
  }
  __syncthreads();

  f32x4 acc[4][4];
#pragma unroll
  for (int mt = 0; mt < 4; ++mt)
#pragma unroll
    for (int nt = 0; nt < 4; ++nt) acc[mt][nt] = (f32x4){};

#pragma unroll
  for (int mt = 0; mt < 4; ++mt) {
#pragma unroll
    for (int kt = 0; kt < 8; ++kt) {
      const f16x8 a = *(const f16x8*)&A16[(mt << 4) + nl][(kt << 5) + koff];
#pragma unroll
      for (int nt = 0; nt < 4; ++nt)
        acc[mt][nt] = __builtin_amdgcn_mfma_f32_16x16x32_f16(a, bfr[nt][kt], acc[mt][nt], 0, 0, 0);
    }
  }
  __syncthreads();

  {
    const int rsub = (lane >> 4) << 2;
#pragma unroll
    for (int nt = 0; nt < 4; ++nt) {
      const int n = (w << 6) + (nt << 4) + nl;
      const float bias = b_ih[n] + b_hh[n];
#pragma unroll
      for (int mt = 0; mt < 4; ++mt)
#pragma unroll
        for (int j = 0; j < 4; ++j)
          A16[(mt << 4) + rsub + j][n] = (_Float16)(acc[mt][nt][j] + bias);
    }
  }
  __syncthreads();

  {
#pragma unroll
    for (int i = 0; i < 8; ++i) {
      const int row = (w << 4) + (i << 1) + (lane >> 5);
      const int col = (lane & 31) << 3;
      *(f16x8*)&xh[(r0 + row) * H_ + col] = *(const f16x8*)&A16[row][col];
    }
  }
}

// ---------------------------------------------------------------------------
// K2: 16-wave scan, 16 WGs x 1024 thr (4 waves/SIMD). Wave w owns rows
// [16w,16w+16) (one m-tile, 8 MFMAs = two 4-deep chains). Lane (quad,nl):
// B col nl (chain cc=nl&3, copy g=nl>>2), k-slice koff=quad*8. After MFMA,
// lane holds C rows quad*4+j (j=0..3) of col nl; copy-group g finishes row
// j=g: 1 tanh, 1 scalar f16 write. Per body: 8 ds_read b128 (4x broadcast,
// loop-invariant addresses) -> 8 MFMA (C_in = cvt(xq) on first chain) ->
// 4 adds -> 3 cndmask -> tanh -> write -> LDS_BARRIER. One barrier/step.
// ---------------------------------------------------------------------------
__global__ __attribute__((amdgpu_flat_work_group_size(1024, 1024)))
__attribute__((amdgpu_waves_per_eu(4, 4))) void k2_rnn(
    const _Float16* __restrict__ xh, const _Float16* __restrict__ Whh16,
    const float* __restrict__ fc1_w, const float* __restrict__ fc1_b,
    const float* __restrict__ fc2_w, const float* __restrict__ fc2_b,
    float* __restrict__ out) {
  __shared__ _Float16 whh_s[H_ * H_];   // 128 KiB staged W_hh (row-major)
  __shared__ _Float16 h16[2][CH][HP];   // ping-pong hidden (fp16)
  __shared__ float    hid_s[CH][H2_ + 4];

  const int tid   = threadIdx.x;
  const int w     = tid >> 6;            // wave 0..15
  const int lane  = tid & 63;
  const int nl    = lane & 15;
  const int quad  = lane >> 4;
  const int cc    = nl & (CH - 1);       // chain (= B col mod 4)
  const int g     = nl >> 2;             // copy group 0..3 -> finishes row j=g
  const int koff  = quad << 3;
  const int wrow  = (w << 4) + (quad << 2);  // C row base of this lane
  const int c0    = blockIdx.x * CH;

  // Stage W_hh into LDS: linear coalesced copy, 1024 thr x 8 rounds x 16 B.
  {
#pragma unroll
    for (int c = 0; c < 8; ++c) {
      const int idx = ((c << 10) + tid) << 3;
      *(f16x8*)&whh_s[idx] = *(const f16x8*)&Whh16[idx];
    }
  }
  // h0 = 0: zero used region [CH][0..256) of buffer 0 (1024 halves).
  if (tid < 128) *(f16x8*)&h16[0][tid >> 5][(tid & 31) << 3] = (f16x8){};
  __syncthreads();

  // A-frags from LDS: W_hh rows 16w+nl, one m-tile = 32 VGPRs (or AGPRs).
  // ds_read results can't be remat'ed past the in-loop "memory"-clobber
  // barriers -> forced register-resident (R4-verified approach).
  f16x8 afr[8];
  {
    const int r = (w << 4) + nl;
#pragma unroll
    for (int kt = 0; kt < 8; ++kt)
      afr[kt] = *(const f16x8*)&whh_s[r * H_ + (kt << 5) + koff];
  }

  // xh stream: chain cc, rows wrow..wrow+3 of each step (C_in of this lane's
  // C fragment). Lanes sharing (cc,quad) duplicate addresses -> dedup.
  const _Float16* xb = xh + (size_t)(c0 + cc) * T_ * H_ + wrow;
  f16x4 xq[4], xn[4];                     // reg-resident relay (proven pattern)
#pragma unroll
  for (int s = 0; s < 4; ++s) xq[s] = *(const f16x4*)&xb[(size_t)s * H_];
#pragma unroll
  for (int s = 0; s < 4; ++s) xn[s] = *(const f16x4*)&xb[(size_t)(4 + s) * H_];

#define BODY(P, S)                                                             \
  {                                                                            \
    f16x8 bfr[8];                                                              \
    _Pragma("unroll")                                                          \
    for (int i = 0; i < 8; ++i)                                                \
      bfr[i] = *(const f16x8*)&h16[P][cc][(i << 5) + koff];                    \
    f32x4 ca = __builtin_amdgcn_mfma_f32_16x16x32_f16(afr[0], bfr[0], cvt4(xq[S]), 0, 0, 0); \
    f32x4 cb = __builtin_amdgcn_mfma_f32_16x16x32_f16(afr[4], bfr[4], (f32x4){}, 0, 0, 0);   \
    _Pragma("unroll")                                                          \
    for (int i = 1; i < 4; ++i) {                                              \
      ca = __builtin_amdgcn_mfma_f32_16x16x32_f16(afr[i], bfr[i], ca, 0, 0, 0);              \
      cb = __builtin_amdgcn_mfma_f32_16x16x32_f16(afr[4 + i], bfr[4 + i], cb, 0, 0, 0);      \
    }                                                                          \
    const f32x4 s4 = ca + cb;                                                  \
    const float u01 = (g & 1) ? s4[1] : s4[0];                                 \
    const float u23 = (g & 1) ? s4[3] : s4[2];                                 \
    const float u   = (g & 2) ? u23 : u01;                                     \
    h16[P ^ 1][cc][wrow + g] = (_Float16)tanh_fast(u);                         \
    LDS_BARRIER();                                                             \
  }

  for (int tt = 0; tt < T_; tt += 4) {
    BODY(0, 0)
    BODY(1, 1)
    BODY(0, 2)
    BODY(1, 3)
    // relay rotate: vmcnt wait lands here, on loads issued 4 bodies ago
#pragma unroll
    for (int s = 0; s < 4; ++s) xq[s] = xn[s];
    const int tn = tt + 8;
#pragma unroll
    for (int s = 0; s < 4; ++s) {
      const size_t ti = (size_t)((tn + s) & (T_ - 1)) * H_;  // wrap; tail unused
      xn[s] = *(const f16x4*)&xb[ti];
    }
  }
#undef BODY

  __syncthreads();  // final h(T) is in h16[0] (last body wrote buf 0)

  // MLP head. fc1: 4 chains x 128 outputs = 512 threads; rest idle.
  if (tid < 512) {
    const int pc = tid >> 7;
    const int o_ = tid & 127;
    float s = fc1_b[o_];
#pragma unroll 8
    for (int k = 0; k < H_; ++k) s += fc1_w[o_ * H_ + k] * (float)h16[0][pc][k];
    hid_s[pc][o_] = fmaxf(s, 0.f);
  }
  __syncthreads();
  if (tid < CH * O_) {
    const int c = tid >> 4, o_ = tid & 15;
    float s = fc2_b[o_];
#pragma unroll 8
    for (int k = 0; k < H2_; ++k) s += fc2_w[o_ * H2_ + k] * hid_s[c][k];
    out[(size_t)(c0 + c) * O_ + o_] = s;
  }
}

extern "C" void kernel_launch(void* const* d_in, const int* in_sizes, int n_in,
                              void* d_out, int out_size, void* d_ws, size_t ws_size,
                              hipStream_t stream) {
  const int*   x     = (const int*)d_in[0];
  const float* emb   = (const float*)d_in[1];
  const float* W_ih  = (const float*)d_in[2];
  const float* W_hh  = (const float*)d_in[3];
  const float* b_ih  = (const float*)d_in[4];
  const float* b_hh  = (const float*)d_in[5];
  const float* fc1_w = (const float*)d_in[6];
  const float* fc1_b = (const float*)d_in[7];
  const float* fc2_w = (const float*)d_in[8];
  const float* fc2_b = (const float*)d_in[9];
  float* outp = (float*)d_out;

  _Float16* xh16  = (_Float16*)d_ws;                    // 64 MiB
  _Float16* Wih16 = xh16 + (size_t)B_ * T_ * H_;        // 128 KiB
  _Float16* Whh16 = Wih16 + (size_t)H_ * E_;            // 128 KiB

  k0_cvt<<<dim3(H_ * E_ / 1024), dim3(256), 0, stream>>>(W_ih, W_hh, Wih16, Whh16);
  k1_xh<<<dim3(B_ * T_ / 64), dim3(256), 0, stream>>>(x, emb, Wih16, b_ih, b_hh, xh16);
  k2_rnn<<<dim3(B_ / CH), dim3(1024), 0, stream>>>(xh16, Whh16, fc1_w, fc1_b, fc2_w, fc2_b, outp);
}